// Round 1
// baseline (785.334 us; speedup 1.0000x reference)
//
#include <hip/hip_runtime.h>
#include <cstdint>
#include <cstddef>

// Problem constants (R,1,C) x, t, (K,C) A, (T,) bar_alpha
#define R_DIM 4096
#define K_DIM 16384
#define C_DIM 512
#define SPLITS 4                 // split-K over the 16384 dimension
#define BM 64                    // rows per workgroup
#define BK 128                   // K (=k-index) tile
#define KRANGE (K_DIM / SPLITS)  // 4096 k's per split
#define NTILES (KRANGE / BK)     // 32 tiles

typedef unsigned short us8 __attribute__((ext_vector_type(8)));
typedef float f32x4 __attribute__((ext_vector_type(4)));
typedef __bf16 bfv8 __attribute__((ext_vector_type(8)));

#define MFMA16(a, b, c) __builtin_amdgcn_mfma_f32_16x16x32_bf16((a), (b), (c), 0, 0, 0)
#define BC(v) __builtin_bit_cast(bfv8, (v))

__device__ __forceinline__ unsigned short f2bf(float v) {
    union { float f; unsigned u; } x; x.f = v;
    unsigned r = x.u + 0x7fffu + ((x.u >> 16) & 1u);  // RNE
    return (unsigned short)(r >> 16);
}
__device__ __forceinline__ float bf2f(unsigned short b) {
    union { unsigned u; float f; } x; x.u = ((unsigned)b) << 16;
    return x.f;
}

// ---------------- workspace layout (bytes) ----------------
#define OFF_AH   ((size_t)0)          // [K][C] bf16 hi   16 MB
#define OFF_AL   ((size_t)16777216)   // [K][C] bf16 lo   16 MB
#define OFF_ATH  ((size_t)33554432)   // [C][K] bf16 hi   16 MB (transposed)
#define OFF_ATL  ((size_t)50331648)   // [C][K] bf16 lo   16 MB
#define OFF_XH   ((size_t)67108864)   // [R][C] bf16 hi    4 MB
#define OFF_XL   ((size_t)71303168)   // [R][C] bf16 lo    4 MB
#define OFF_ASQ  ((size_t)75497472)   // [K] f32          64 KB
#define OFF_ROWP ((size_t)75563008)   // [R] float4       64 KB  {sa, 0.5*sa*sa, inv1m*log2e, inv1m}
#define OFF_PO   ((size_t)75628544)   // [R][SPLITS][C] f32  32 MB
#define OFF_PM   ((size_t)109182976)  // [R][SPLITS] f32  64 KB
#define OFF_PL   ((size_t)109248512)  // [R][SPLITS] f32  64 KB
#define WS_NEED  ((size_t)109314048)

// ---------------- LDS layout for fused kernel (bytes) ----------------
#define SMEM_A   0       // staged chunk hi: [128 rows][128 cols] bf16, XOR-swizzled  (32 KB)
#define SMEM_A2  32768   // staged chunk lo                                           (32 KB)
#define SMEM_U   65536   // u hi [64][128] bf16 swizzled                              (16 KB)
#define SMEM_U2  81920   // u lo                                                      (16 KB)
#define SMEM_MX  98304   // float[2][64] tile-max exchange
#define SMEM_SM  98816   // float[2][64] tile-sum exchange
#define SMEM_TOT 99328

// ======================= prep kernels =======================

__global__ void k_rows(const int* __restrict__ t, const float* __restrict__ bar_alpha,
                       float4* __restrict__ rowp) {
    int r = blockIdx.x * 256 + threadIdx.x;
    if (r >= R_DIM) return;
    float ba = bar_alpha[t[r]];
    float sa = sqrtf(ba);
    float inv = 1.0f / (1.0f - ba);
    // match reference: d2 uses sa**2 (not ba)
    rowp[r] = make_float4(sa, 0.5f * sa * sa, inv * 1.4426950408889634f, inv);
}

__global__ void k_splitx(const float* __restrict__ x, us8* __restrict__ xh, us8* __restrict__ xl) {
    int i = blockIdx.x * 256 + threadIdx.x;   // group of 8 elements
    if (i >= R_DIM * C_DIM / 8) return;
    const float4* x4 = (const float4*)x + (size_t)i * 2;
    float v[8];
    float4 a = x4[0], b = x4[1];
    v[0]=a.x; v[1]=a.y; v[2]=a.z; v[3]=a.w; v[4]=b.x; v[5]=b.y; v[6]=b.z; v[7]=b.w;
    us8 h, l;
#pragma unroll
    for (int j = 0; j < 8; ++j) {
        unsigned short hb = f2bf(v[j]);
        h[j] = hb;
        l[j] = f2bf(v[j] - bf2f(hb));
    }
    xh[i] = h; xl[i] = l;
}

// split A into hi/lo and build transposed copies via LDS tile transpose
__global__ __launch_bounds__(256) void k_prepA(const float* __restrict__ A,
        unsigned short* __restrict__ Ah, unsigned short* __restrict__ Al,
        unsigned short* __restrict__ Ath, unsigned short* __restrict__ Atl) {
    __shared__ unsigned short lh[64][72];
    __shared__ unsigned short ll[64][72];
    int kb = blockIdx.x >> 3, cb = blockIdx.x & 7;   // K/64=256 x C/64=8
    int tid = threadIdx.x;
    int cl = tid & 63, tq = tid >> 6;
#pragma unroll
    for (int ii = 0; ii < 16; ++ii) {
        int kl = tq * 16 + ii;
        size_t gi = (size_t)(kb * 64 + kl) * C_DIM + cb * 64 + cl;
        float v = A[gi];
        unsigned short h = f2bf(v);
        unsigned short l = f2bf(v - bf2f(h));
        Ah[gi] = h; Al[gi] = l;
        lh[kl][cl] = h; ll[kl][cl] = l;
    }
    __syncthreads();
    int kl2 = tid & 63;
#pragma unroll
    for (int ii = 0; ii < 16; ++ii) {
        int cl2 = tq * 16 + ii;
        size_t go = (size_t)(cb * 64 + cl2) * K_DIM + kb * 64 + kl2;
        Ath[go] = lh[kl2][cl2];
        Atl[go] = ll[kl2][cl2];
    }
}

__global__ void k_asq(const float* __restrict__ A, float* __restrict__ Asq) {
    int wid = threadIdx.x >> 6, lane = threadIdx.x & 63;
    int k = blockIdx.x * 4 + wid;
    const float4* a4 = (const float4*)(A + (size_t)k * C_DIM);
    float s = 0.f;
#pragma unroll
    for (int j = 0; j < 2; ++j) {
        float4 v = a4[lane * 2 + j];
        s += v.x * v.x + v.y * v.y + v.z * v.z + v.w * v.w;
    }
#pragma unroll
    for (int off = 32; off; off >>= 1) s += __shfl_xor(s, off);
    if (lane == 0) Asq[k] = s;
}

// ======================= fused flash-style kernel =======================
// grid = (R/BM) * SPLITS = 256 blocks, 512 threads (8 waves: wr=wid>>1 in 0..3 rows, wc=wid&1)
__global__ __launch_bounds__(512, 2) void k_fused(
    const unsigned short* __restrict__ Ah, const unsigned short* __restrict__ Al,
    const unsigned short* __restrict__ Ath, const unsigned short* __restrict__ Atl,
    const unsigned short* __restrict__ xh, const unsigned short* __restrict__ xl,
    const float* __restrict__ Asq, const float4* __restrict__ rowp,
    float* __restrict__ pO, float* __restrict__ pM, float* __restrict__ pL)
{
    extern __shared__ char smem[];
    const int tid = threadIdx.x;
    const int lane = tid & 63, wid = tid >> 6;
    const int wr = wid >> 1, wc = wid & 1;
    const int l15 = lane & 15, l4 = lane >> 4;
    const int bid = blockIdx.x;
    const int rb = (bid >> 2) * BM;
    const int split = bid & (SPLITS - 1);
    const int kbase0 = split * KRANGE;

    // per-lane params for the 4 D-layout rows this lane owns: m = wr*16 + l4*4 + j
    float sa[4], hb[4], ce[4];
#pragma unroll
    for (int j = 0; j < 4; ++j) {
        float4 p = rowp[rb + wr * 16 + l4 * 4 + j];
        sa[j] = p.x; hb[j] = p.y; ce[j] = p.z;
    }
    float Mr[4], Lr[4];
#pragma unroll
    for (int j = 0; j < 4; ++j) { Mr[j] = -1e30f; Lr[j] = 0.f; }
    f32x4 of[4][4];   // [c-chunk][c-frag], rows via reg index
#pragma unroll
    for (int a = 0; a < 4; ++a)
#pragma unroll
        for (int b = 0; b < 4; ++b) of[a][b] = (f32x4){0.f, 0.f, 0.f, 0.f};

    const int xrowoff = (rb + wr * 16 + l15) * C_DIM;

    for (int kt = 0; kt < NTILES; ++kt) {
        const int kbase = kbase0 + kt * BK;
        f32x4 sf[4];
#pragma unroll
        for (int f = 0; f < 4; ++f) sf[f] = (f32x4){0.f, 0.f, 0.f, 0.f};

        // ---------- Phase A: S[64][128] = (xh+xl)(Ah+Al)^T over C ----------
        for (int cc = 0; cc < 4; ++cc) {
            // stage A chunk [128 k][128 c] hi+lo, XOR swizzle byte^=(row&7)<<4
#pragma unroll
            for (int i = 0; i < 4; ++i) {
                int g = tid + i * 512;
                int kl = g >> 4, c8 = g & 15;
                size_t goff = (size_t)(kbase + kl) * C_DIM + cc * 128 + c8 * 8;
                us8 vh = *(const us8*)(Ah + goff);
                us8 vl = *(const us8*)(Al + goff);
                int sw = (kl * 256 + c8 * 16) ^ ((kl & 7) << 4);
                *(us8*)(smem + SMEM_A + sw) = vh;
                *(us8*)(smem + SMEM_A2 + sw) = vl;
            }
            __syncthreads();
            us8 xhf[4], xlf[4];
#pragma unroll
            for (int cs = 0; cs < 4; ++cs) {
                int xoff = xrowoff + cc * 128 + cs * 32 + l4 * 8;
                xhf[cs] = *(const us8*)(xh + xoff);
                xlf[cs] = *(const us8*)(xl + xoff);
            }
#pragma unroll
            for (int cs = 0; cs < 4; ++cs) {
#pragma unroll
                for (int f = 0; f < 4; ++f) {
                    int row = wc * 64 + f * 16 + l15;          // k-index within tile
                    int byte = (row * 256 + cs * 64 + l4 * 16) ^ ((row & 7) << 4);
                    bfv8 qh = *(const bfv8*)(smem + SMEM_A + byte);
                    bfv8 ql = *(const bfv8*)(smem + SMEM_A2 + byte);
                    sf[f] = MFMA16(BC(xhf[cs]), qh, sf[f]);
                    sf[f] = MFMA16(BC(xhf[cs]), ql, sf[f]);
                    sf[f] = MFMA16(BC(xlf[cs]), qh, sf[f]);
                }
            }
            __syncthreads();
        }

        // ---------- Phase B: online softmax ----------
        float g[4][4];   // [f][reg]
#pragma unroll
        for (int f = 0; f < 4; ++f) {
            float asq = Asq[kbase + wc * 64 + f * 16 + l15];
#pragma unroll
            for (int j = 0; j < 4; ++j) g[f][j] = sa[j] * sf[f][j] - hb[j] * asq;
        }
        float tmax[4];
#pragma unroll
        for (int j = 0; j < 4; ++j)
            tmax[j] = fmaxf(fmaxf(g[0][j], g[1][j]), fmaxf(g[2][j], g[3][j]));
#pragma unroll
        for (int off = 1; off < 16; off <<= 1)
#pragma unroll
            for (int j = 0; j < 4; ++j) tmax[j] = fmaxf(tmax[j], __shfl_xor(tmax[j], off));
        float* smax = (float*)(smem + SMEM_MX);
        if (l15 == 0) {
#pragma unroll
            for (int j = 0; j < 4; ++j) smax[wc * 64 + wr * 16 + l4 * 4 + j] = tmax[j];
        }
        __syncthreads();
        float Mn[4], al[4];
#pragma unroll
        for (int j = 0; j < 4; ++j) {
            float other = smax[(wc ^ 1) * 64 + wr * 16 + l4 * 4 + j];
            float tm = fmaxf(tmax[j], other);
            Mn[j] = fmaxf(Mr[j], tm);
            al[j] = exp2f((Mr[j] - Mn[j]) * ce[j]);
        }
        float u[4][4], tsum[4] = {0.f, 0.f, 0.f, 0.f};
#pragma unroll
        for (int f = 0; f < 4; ++f)
#pragma unroll
            for (int j = 0; j < 4; ++j) {
                u[f][j] = exp2f((g[f][j] - Mn[j]) * ce[j]);
                tsum[j] += u[f][j];
            }
#pragma unroll
        for (int off = 1; off < 16; off <<= 1)
#pragma unroll
            for (int j = 0; j < 4; ++j) tsum[j] += __shfl_xor(tsum[j], off);
        float* ssum = (float*)(smem + SMEM_SM);
        if (l15 == 0) {
#pragma unroll
            for (int j = 0; j < 4; ++j) ssum[wc * 64 + wr * 16 + l4 * 4 + j] = tsum[j];
        }
        // write u (bf16 hi/lo) to LDS for GEMM2 A-operand
#pragma unroll
        for (int f = 0; f < 4; ++f)
#pragma unroll
            for (int j = 0; j < 4; ++j) {
                int m_loc = wr * 16 + l4 * 4 + j;
                int k_loc = wc * 64 + f * 16 + l15;
                int byte = (m_loc * 256 + k_loc * 2) ^ ((m_loc & 7) << 4);
                unsigned short uh = f2bf(u[f][j]);
                *(unsigned short*)(smem + SMEM_U + byte) = uh;
                *(unsigned short*)(smem + SMEM_U2 + byte) = f2bf(u[f][j] - bf2f(uh));
            }
        __syncthreads();
#pragma unroll
        for (int j = 0; j < 4; ++j) {
            float others = ssum[(wc ^ 1) * 64 + wr * 16 + l4 * 4 + j];
            Lr[j] = Lr[j] * al[j] + tsum[j] + others;
            Mr[j] = Mn[j];
        }
#pragma unroll
        for (int a = 0; a < 4; ++a)
#pragma unroll
            for (int b = 0; b < 4; ++b)
#pragma unroll
                for (int j = 0; j < 4; ++j) of[a][b][j] *= al[j];

        // ---------- Phase C: O[64][512] += u * A_tile ----------
        us8 uhf[4], ulf[4];
#pragma unroll
        for (int ks = 0; ks < 4; ++ks) {
            int m_loc = wr * 16 + l15;
            int byte = (m_loc * 256 + ks * 64 + l4 * 16) ^ ((m_loc & 7) << 4);
            uhf[ks] = *(const us8*)(smem + SMEM_U + byte);
            ulf[ks] = *(const us8*)(smem + SMEM_U2 + byte);
        }
#pragma unroll
        for (int cc2 = 0; cc2 < 4; ++cc2) {
            // stage At chunk [128 c][128 k] hi+lo
#pragma unroll
            for (int i = 0; i < 4; ++i) {
                int g2 = tid + i * 512;
                int cl = g2 >> 4, k8 = g2 & 15;
                size_t goff = (size_t)(cc2 * 128 + cl) * K_DIM + kbase + k8 * 8;
                us8 vh = *(const us8*)(Ath + goff);
                us8 vl = *(const us8*)(Atl + goff);
                int sw = (cl * 256 + k8 * 16) ^ ((cl & 7) << 4);
                *(us8*)(smem + SMEM_A + sw) = vh;
                *(us8*)(smem + SMEM_A2 + sw) = vl;
            }
            __syncthreads();
#pragma unroll
            for (int f = 0; f < 4; ++f) {
                int c_l = wc * 64 + f * 16 + l15;
#pragma unroll
                for (int ks = 0; ks < 4; ++ks) {
                    int byte = (c_l * 256 + ks * 64 + l4 * 16) ^ ((c_l & 7) << 4);
                    bfv8 qh = *(const bfv8*)(smem + SMEM_A + byte);
                    bfv8 ql = *(const bfv8*)(smem + SMEM_A2 + byte);
                    of[cc2][f] = MFMA16(BC(uhf[ks]), qh, of[cc2][f]);
                    of[cc2][f] = MFMA16(BC(uhf[ks]), ql, of[cc2][f]);
                    of[cc2][f] = MFMA16(BC(ulf[ks]), qh, of[cc2][f]);
                }
            }
            __syncthreads();
        }
    }

    // ---------- write split partials ----------
#pragma unroll
    for (int cc2 = 0; cc2 < 4; ++cc2)
#pragma unroll
        for (int f = 0; f < 4; ++f)
#pragma unroll
            for (int j = 0; j < 4; ++j) {
                int gm = rb + wr * 16 + l4 * 4 + j;
                int cg = cc2 * 128 + wc * 64 + f * 16 + l15;
                pO[((size_t)gm * SPLITS + split) * C_DIM + cg] = of[cc2][f][j];
            }
    if (wc == 0 && l15 == 0) {
#pragma unroll
        for (int j = 0; j < 4; ++j) {
            int gm = rb + wr * 16 + l4 * 4 + j;
            pM[gm * SPLITS + split] = Mr[j];
            pL[gm * SPLITS + split] = Lr[j];
        }
    }
}

// ======================= split-K combine =======================
__global__ void k_combine(const float* __restrict__ pO, const float* __restrict__ pM,
                          const float* __restrict__ pL, const float4* __restrict__ rowp,
                          float* __restrict__ out) {
    int r = blockIdx.x;
    int tid = threadIdx.x;   // 128 threads, 4 c's each
    float ce = rowp[r].z;
    float Ms[SPLITS], Ls[SPLITS];
    float M = -1e30f;
#pragma unroll
    for (int s = 0; s < SPLITS; ++s) {
        Ms[s] = pM[r * SPLITS + s];
        Ls[s] = pL[r * SPLITS + s];
        M = fmaxf(M, Ms[s]);
    }
    float es[SPLITS], L = 0.f;
#pragma unroll
    for (int s = 0; s < SPLITS; ++s) { es[s] = exp2f((Ms[s] - M) * ce); L += Ls[s] * es[s]; }
    float invL = 1.0f / L;
    f32x4 acc = (f32x4){0.f, 0.f, 0.f, 0.f};
#pragma unroll
    for (int s = 0; s < SPLITS; ++s) {
        f32x4 v = *(const f32x4*)(pO + ((size_t)r * SPLITS + s) * C_DIM + tid * 4);
        acc += v * es[s];
    }
    acc *= invL;
    *(f32x4*)(out + (size_t)r * C_DIM + tid * 4) = acc;
}

// ======================= launch =======================
extern "C" void kernel_launch(void* const* d_in, const int* in_sizes, int n_in,
                              void* d_out, int out_size, void* d_ws, size_t ws_size,
                              hipStream_t stream) {
    const float* x = (const float*)d_in[0];
    const int* t = (const int*)d_in[1];
    const float* A = (const float*)d_in[2];
    const float* bar_alpha = (const float*)d_in[3];
    float* out = (float*)d_out;
    char* ws = (char*)d_ws;
    if (ws_size < WS_NEED) return;  // workspace too small -> fail validation visibly

    unsigned short* Ah = (unsigned short*)(ws + OFF_AH);
    unsigned short* Al = (unsigned short*)(ws + OFF_AL);
    unsigned short* Ath = (unsigned short*)(ws + OFF_ATH);
    unsigned short* Atl = (unsigned short*)(ws + OFF_ATL);
    unsigned short* Xh = (unsigned short*)(ws + OFF_XH);
    unsigned short* Xl = (unsigned short*)(ws + OFF_XL);
    float* Asq = (float*)(ws + OFF_ASQ);
    float4* rowp = (float4*)(ws + OFF_ROWP);
    float* pO = (float*)(ws + OFF_PO);
    float* pM = (float*)(ws + OFF_PM);
    float* pL = (float*)(ws + OFF_PL);

    (void)hipFuncSetAttribute((const void*)k_fused,
                              hipFuncAttributeMaxDynamicSharedMemorySize, SMEM_TOT);

    k_rows<<<R_DIM / 256, 256, 0, stream>>>(t, bar_alpha, rowp);
    k_splitx<<<(R_DIM * C_DIM / 8) / 256, 256, 0, stream>>>(x, (us8*)Xh, (us8*)Xl);
    k_prepA<<<(K_DIM / 64) * (C_DIM / 64), 256, 0, stream>>>(A, Ah, Al, Ath, Atl);
    k_asq<<<K_DIM / 4, 256, 0, stream>>>(A, Asq);
    k_fused<<<(R_DIM / BM) * SPLITS, 512, SMEM_TOT, stream>>>(Ah, Al, Ath, Atl, Xh, Xl,
                                                              Asq, rowp, pO, pM, pL);
    k_combine<<<R_DIM, 128, 0, stream>>>(pO, pM, pL, rowp, out);
}

// Round 2
// 751.469 us; speedup vs baseline: 1.0451x; 1.0451x over previous
//
#include <hip/hip_runtime.h>
#include <cstdint>
#include <cstddef>

// Problem constants (R,1,C) x, t, (K,C) A, (T,) bar_alpha
#define R_DIM 4096
#define K_DIM 16384
#define C_DIM 512
#define SPLITS 4                 // split over the 16384 k-dimension
#define BM 64                    // rows per workgroup
#define BK 128                   // k-tile
#define KRANGE (K_DIM / SPLITS)  // 4096
#define NTILES (KRANGE / BK)     // 32
#define GTILES (K_DIM / BK)      // 128 global tiles

typedef unsigned short us8 __attribute__((ext_vector_type(8)));
typedef float f32x4 __attribute__((ext_vector_type(4)));
typedef __bf16 bfv8 __attribute__((ext_vector_type(8)));

#define MFMA16(a, b, c) __builtin_amdgcn_mfma_f32_16x16x32_bf16((a), (b), (c), 0, 0, 0)
#define BC(v) __builtin_bit_cast(bfv8, (v))

__device__ __forceinline__ unsigned short f2bf(float v) {
    union { float f; unsigned u; } x; x.f = v;
    unsigned r = x.u + 0x7fffu + ((x.u >> 16) & 1u);  // RNE
    return (unsigned short)(r >> 16);
}
__device__ __forceinline__ float bf2f(unsigned short b) {
    union { unsigned u; float f; } x; x.u = ((unsigned)b) << 16;
    return x.f;
}

// async global->LDS, 16B per lane. LDS dest is wave-uniform base + lane*16 (we
// pass the per-lane linear address; firstlane base + lane*16 is identical).
__device__ __forceinline__ void gload16(const char* g, char* l) {
    __builtin_amdgcn_global_load_lds(
        (const __attribute__((address_space(1))) void*)g,
        (__attribute__((address_space(3))) void*)l, 16, 0, 0);
}

// ---------------- workspace layout (bytes) ----------------
// Pre-swizzled chunk images: for each global k-tile gt (128 of them) and chunk
// j (8 of them), a contiguous 32KB block = exact LDS byte image (16KB hi,16KB lo).
#define OFF_IMGA ((size_t)0)          // [GTILES][8][32768]  32 MB   [128k][64c] images
#define OFF_IMGC ((size_t)33554432)   // [GTILES][8][32768]  32 MB   [64c][128k] images
#define OFF_XH   ((size_t)67108864)   // [R][C] bf16 hi    4 MB
#define OFF_XL   ((size_t)71303168)   // [R][C] bf16 lo    4 MB
#define OFF_ASQ  ((size_t)75497472)   // [K] f32          64 KB
#define OFF_ROWP ((size_t)75563008)   // [R] float4       64 KB  {sa, 0.5*sa*sa, inv*log2e, inv}
#define OFF_PO   ((size_t)75628544)   // [R][SPLITS][C] f32  32 MB
#define OFF_PM   ((size_t)109182976)  // [R][SPLITS] f32  64 KB
#define OFF_PL   ((size_t)109248512)  // [R][SPLITS] f32  64 KB
#define WS_NEED  ((size_t)109314048)

// ---------------- LDS layout (bytes) ----------------
#define SM_BUF0 0        // staging buffer 0: 32 KB (hi 16K, lo 16K)
#define SM_BUF1 32768    // staging buffer 1: 32 KB
#define SM_U    65536    // u hi [64m][128k] bf16 swizzled  16 KB
#define SM_U2   81920    // u lo                            16 KB
#define SM_MX   98304    // float[2][64] tile-max exchange
#define SM_SM   98816    // float[2][64] tile-sum exchange
#define SM_TOT  99328

// ======================= prep kernels =======================

__global__ void k_rows(const int* __restrict__ t, const float* __restrict__ bar_alpha,
                       float4* __restrict__ rowp) {
    int r = blockIdx.x * 256 + threadIdx.x;
    if (r >= R_DIM) return;
    float ba = bar_alpha[t[r]];
    float sa = sqrtf(ba);
    float inv = 1.0f / (1.0f - ba);
    rowp[r] = make_float4(sa, 0.5f * sa * sa, inv * 1.4426950408889634f, inv);
}

__global__ void k_splitx(const float* __restrict__ x, us8* __restrict__ xh, us8* __restrict__ xl) {
    int i = blockIdx.x * 256 + threadIdx.x;   // group of 8 elements
    if (i >= R_DIM * C_DIM / 8) return;
    const float4* x4 = (const float4*)x + (size_t)i * 2;
    float v[8];
    float4 a = x4[0], b = x4[1];
    v[0]=a.x; v[1]=a.y; v[2]=a.z; v[3]=a.w; v[4]=b.x; v[5]=b.y; v[6]=b.z; v[7]=b.w;
    us8 h, l;
#pragma unroll
    for (int j = 0; j < 8; ++j) {
        unsigned short hb = f2bf(v[j]);
        h[j] = hb;
        l[j] = f2bf(v[j] - bf2f(hb));
    }
    xh[i] = h; xl[i] = l;
}

// Phase-A chunk images: block = (gt, j). Image position for (kl row, cb 16B-col-group):
// pos = kl*128 + ((cb*16) ^ ((kl&7)<<4)); content = A[gt*128+kl][j*64 + cb*8 .. +8]
__global__ __launch_bounds__(256) void k_imgA(const float* __restrict__ A, char* __restrict__ img) {
    int gt = blockIdx.x >> 3, j = blockIdx.x & 7;
    char* base = img + (size_t)blockIdx.x * 32768;
    int t = threadIdx.x;
#pragma unroll
    for (int it = 0; it < 4; ++it) {
        int p = t + it * 256;
        int kl = p >> 3, cb = p & 7;
        const float* src = A + (size_t)(gt * 128 + kl) * C_DIM + j * 64 + cb * 8;
        us8 h, l;
#pragma unroll
        for (int q = 0; q < 8; ++q) {
            float v = src[q];
            unsigned short hb = f2bf(v);
            h[q] = hb; l[q] = f2bf(v - bf2f(hb));
        }
        int pos = kl * 128 + ((cb * 16) ^ ((kl & 7) << 4));
        *(us8*)(base + pos) = h;
        *(us8*)(base + 16384 + pos) = l;
    }
}

// Phase-C chunk images (transposed): block = (gt, j). Position for (cl c-row, kb 16B-k-group):
// pos = cl*256 + ((kb*16) ^ ((cl&7)<<4)); content = A[gt*128 + kb*8 + q][j*64 + cl], q=0..7
__global__ __launch_bounds__(256) void k_imgC(const float* __restrict__ A, char* __restrict__ img) {
    int gt = blockIdx.x >> 3, j = blockIdx.x & 7;
    char* base = img + (size_t)blockIdx.x * 32768;
    int t = threadIdx.x;
#pragma unroll
    for (int it = 0; it < 4; ++it) {
        int p = t + it * 256;
        int cl = p & 63, kb = p >> 6;
        us8 h, l;
#pragma unroll
        for (int q = 0; q < 8; ++q) {
            float v = A[(size_t)(gt * 128 + kb * 8 + q) * C_DIM + j * 64 + cl];
            unsigned short hb = f2bf(v);
            h[q] = hb; l[q] = f2bf(v - bf2f(hb));
        }
        int pos = cl * 256 + ((kb * 16) ^ ((cl & 7) << 4));
        *(us8*)(base + pos) = h;
        *(us8*)(base + 16384 + pos) = l;
    }
}

__global__ void k_asq(const float* __restrict__ A, float* __restrict__ Asq) {
    int wid = threadIdx.x >> 6, lane = threadIdx.x & 63;
    int k = blockIdx.x * 4 + wid;
    const float4* a4 = (const float4*)(A + (size_t)k * C_DIM);
    float s = 0.f;
#pragma unroll
    for (int j = 0; j < 2; ++j) {
        float4 v = a4[lane * 2 + j];
        s += v.x * v.x + v.y * v.y + v.z * v.z + v.w * v.w;
    }
#pragma unroll
    for (int off = 32; off; off >>= 1) s += __shfl_xor(s, off);
    if (lane == 0) Asq[k] = s;
}

// ======================= fused flash-style kernel =======================
// grid = 64 rowblocks * 4 splits (blockIdx = rb*4+split), 512 threads, 8 waves
// (wr = wid>>1 row-group, wc = wid&1). 2-phase pipeline: every chunk issues the
// NEXT chunk's global_load_lds before its MFMAs; __syncthreads drains.
__global__ __launch_bounds__(512, 2) void k_fused(
    const char* __restrict__ imgA, const char* __restrict__ imgC,
    const unsigned short* __restrict__ xh, const unsigned short* __restrict__ xl,
    const float* __restrict__ Asq, const float4* __restrict__ rowp,
    float* __restrict__ pO, float* __restrict__ pM, float* __restrict__ pL)
{
    extern __shared__ char smem[];
    const int tid = threadIdx.x;
    const int lane = tid & 63, wid = tid >> 6;
    const int wr = wid >> 1, wc = wid & 1;
    const int l15 = lane & 15, l4 = lane >> 4;
    const int rb = (blockIdx.x >> 2) * BM;
    const int split = blockIdx.x & (SPLITS - 1);

    float sa[4], hb[4], ce[4];
#pragma unroll
    for (int q = 0; q < 4; ++q) {
        float4 p = rowp[rb + wr * 16 + l4 * 4 + q];
        sa[q] = p.x; hb[q] = p.y; ce[q] = p.z;
    }
    float Mr[4], Lr[4];
#pragma unroll
    for (int q = 0; q < 4; ++q) { Mr[q] = -1e30f; Lr[q] = 0.f; }
    f32x4 of[8][2];   // [c-chunk j][c-frag f]
#pragma unroll
    for (int a = 0; a < 8; ++a)
#pragma unroll
        for (int b = 0; b < 2; ++b) of[a][b] = (f32x4){0.f, 0.f, 0.f, 0.f};

    const int xrow = (rb + wr * 16 + l15) * C_DIM;
    const int stg = tid * 16;

    // prologue: stage A(tile 0, chunk 0) into BUF0
    {
        const char* s = imgA + (size_t)(split * NTILES) * 8 * 32768 + stg;
        char* d = smem + SM_BUF0 + stg;
#pragma unroll
        for (int i = 0; i < 4; ++i) gload16(s + i * 8192, d + i * 8192);
    }
    __syncthreads();
    int cur = 0;

    for (int kt = 0; kt < NTILES; ++kt) {
        const int gt = split * NTILES + kt;
        const int kbase = gt * BK;
        f32x4 sf[4];
#pragma unroll
        for (int f = 0; f < 4; ++f) sf[f] = (f32x4){0.f, 0.f, 0.f, 0.f};

        // ---------- Phase A: S[64m][128k] = (xh+xl)(Ah+Al)^T, 8 chunks of 64 c ----------
        us8 xbh[2][2], xbl[2][2];
#pragma unroll
        for (int cs = 0; cs < 2; ++cs) {   // cold load for chunk 0
            int off = xrow + 0 * 64 + cs * 32 + l4 * 8;
            xbh[0][cs] = *(const us8*)(xh + off);
            xbl[0][cs] = *(const us8*)(xl + off);
        }
#pragma unroll
        for (int j = 0; j < 8; ++j) {
            // stage next chunk (A j+1, or C 0 when j==7) into buf^1
            {
                const char* s = (j < 7) ? imgA + ((size_t)gt * 8 + j + 1) * 32768
                                        : imgC + ((size_t)gt * 8 + 0) * 32768;
                char* d = smem + (cur ? SM_BUF0 : SM_BUF1) + stg;
#pragma unroll
                for (int i = 0; i < 4; ++i) gload16(s + stg + i * 8192, d + i * 8192);
            }
            // prefetch next chunk's x frags (landed by this chunk's barrier)
            if (j < 7) {
#pragma unroll
                for (int cs = 0; cs < 2; ++cs) {
                    int off = xrow + (j + 1) * 64 + cs * 32 + l4 * 8;
                    xbh[(j + 1) & 1][cs] = *(const us8*)(xh + off);
                    xbl[(j + 1) & 1][cs] = *(const us8*)(xl + off);
                }
            }
            // MFMA on current buffer
            const char* B = smem + (cur ? SM_BUF1 : SM_BUF0);
#pragma unroll
            for (int cs = 0; cs < 2; ++cs) {
#pragma unroll
                for (int f = 0; f < 4; ++f) {
                    int row = wc * 64 + f * 16 + l15;              // k-index in tile
                    int byte = row * 128 + ((cs * 64 + l4 * 16) ^ ((row & 7) << 4));
                    bfv8 qh = *(const bfv8*)(B + byte);
                    bfv8 ql = *(const bfv8*)(B + 16384 + byte);
                    sf[f] = MFMA16(BC(xbh[j & 1][cs]), qh, sf[f]);
                    sf[f] = MFMA16(BC(xbh[j & 1][cs]), ql, sf[f]);
                    sf[f] = MFMA16(BC(xbl[j & 1][cs]), qh, sf[f]);
                }
            }
            __syncthreads();
            cur ^= 1;
        }

        // ---------- Phase B: online softmax ----------
        float g[4][4];
#pragma unroll
        for (int f = 0; f < 4; ++f) {
            float asq = Asq[kbase + wc * 64 + f * 16 + l15];
#pragma unroll
            for (int q = 0; q < 4; ++q) g[f][q] = sa[q] * sf[f][q] - hb[q] * asq;
        }
        float tmax[4];
#pragma unroll
        for (int q = 0; q < 4; ++q)
            tmax[q] = fmaxf(fmaxf(g[0][q], g[1][q]), fmaxf(g[2][q], g[3][q]));
#pragma unroll
        for (int off = 1; off < 16; off <<= 1)
#pragma unroll
            for (int q = 0; q < 4; ++q) tmax[q] = fmaxf(tmax[q], __shfl_xor(tmax[q], off));
        float* smax = (float*)(smem + SM_MX);
        if (l15 == 0) {
#pragma unroll
            for (int q = 0; q < 4; ++q) smax[wc * 64 + wr * 16 + l4 * 4 + q] = tmax[q];
        }
        __syncthreads();
        float Mn[4], al[4];
#pragma unroll
        for (int q = 0; q < 4; ++q) {
            float other = smax[(wc ^ 1) * 64 + wr * 16 + l4 * 4 + q];
            float tm = fmaxf(tmax[q], other);
            Mn[q] = fmaxf(Mr[q], tm);
            al[q] = exp2f((Mr[q] - Mn[q]) * ce[q]);
        }
        float u[4][4], tsum[4] = {0.f, 0.f, 0.f, 0.f};
#pragma unroll
        for (int f = 0; f < 4; ++f)
#pragma unroll
            for (int q = 0; q < 4; ++q) {
                u[f][q] = exp2f((g[f][q] - Mn[q]) * ce[q]);
                tsum[q] += u[f][q];
            }
#pragma unroll
        for (int off = 1; off < 16; off <<= 1)
#pragma unroll
            for (int q = 0; q < 4; ++q) tsum[q] += __shfl_xor(tsum[q], off);
        float* ssum = (float*)(smem + SM_SM);
        if (l15 == 0) {
#pragma unroll
            for (int q = 0; q < 4; ++q) ssum[wc * 64 + wr * 16 + l4 * 4 + q] = tsum[q];
        }
        // write u (bf16 hi/lo) to LDS for GEMM2 A-operand
#pragma unroll
        for (int f = 0; f < 4; ++f)
#pragma unroll
            for (int q = 0; q < 4; ++q) {
                int m_loc = wr * 16 + l4 * 4 + q;
                int k_loc = wc * 64 + f * 16 + l15;
                int byte = (m_loc * 256 + k_loc * 2) ^ ((m_loc & 7) << 4);
                unsigned short uh = f2bf(u[f][q]);
                *(unsigned short*)(smem + SM_U + byte) = uh;
                *(unsigned short*)(smem + SM_U2 + byte) = f2bf(u[f][q] - bf2f(uh));
            }
        __syncthreads();
#pragma unroll
        for (int q = 0; q < 4; ++q) {
            float others = ssum[(wc ^ 1) * 64 + wr * 16 + l4 * 4 + q];
            Lr[q] = Lr[q] * al[q] + tsum[q] + others;
            Mr[q] = Mn[q];
        }
#pragma unroll
        for (int a = 0; a < 8; ++a)
#pragma unroll
            for (int b = 0; b < 2; ++b)
#pragma unroll
                for (int q = 0; q < 4; ++q) of[a][b][q] *= al[q];

        // ---------- Phase C: O[64m][512c] += u * A_tile, 8 chunks of 64 c ----------
        us8 uhf[4], ulf[4];
#pragma unroll
        for (int ks = 0; ks < 4; ++ks) {
            int m_loc = wr * 16 + l15;
            int byte = (m_loc * 256 + ks * 64 + l4 * 16) ^ ((m_loc & 7) << 4);
            uhf[ks] = *(const us8*)(smem + SM_U + byte);
            ulf[ks] = *(const us8*)(smem + SM_U2 + byte);
        }
#pragma unroll
        for (int j = 0; j < 8; ++j) {
            // stage next chunk (C j+1, or next tile's A 0)
            if (j < 7) {
                const char* s = imgC + ((size_t)gt * 8 + j + 1) * 32768;
                char* d = smem + (cur ? SM_BUF0 : SM_BUF1) + stg;
#pragma unroll
                for (int i = 0; i < 4; ++i) gload16(s + stg + i * 8192, d + i * 8192);
            } else if (kt < NTILES - 1) {
                const char* s = imgA + ((size_t)(gt + 1) * 8 + 0) * 32768;
                char* d = smem + (cur ? SM_BUF0 : SM_BUF1) + stg;
#pragma unroll
                for (int i = 0; i < 4; ++i) gload16(s + stg + i * 8192, d + i * 8192);
            }
            const char* B = smem + (cur ? SM_BUF1 : SM_BUF0);
#pragma unroll
            for (int f = 0; f < 2; ++f) {
                int cl = wc * 32 + f * 16 + l15;                   // c-row in chunk
#pragma unroll
                for (int ks = 0; ks < 4; ++ks) {
                    int byte = cl * 256 + ((ks * 64 + l4 * 16) ^ ((cl & 7) << 4));
                    bfv8 qh = *(const bfv8*)(B + byte);
                    bfv8 ql = *(const bfv8*)(B + 16384 + byte);
                    of[j][f] = MFMA16(BC(uhf[ks]), qh, of[j][f]);
                    of[j][f] = MFMA16(BC(uhf[ks]), ql, of[j][f]);
                    of[j][f] = MFMA16(BC(ulf[ks]), qh, of[j][f]);
                }
            }
            __syncthreads();
            cur ^= 1;
        }
    }

    // ---------- write split partials ----------
#pragma unroll
    for (int j = 0; j < 8; ++j)
#pragma unroll
        for (int f = 0; f < 2; ++f)
#pragma unroll
            for (int q = 0; q < 4; ++q) {
                int gm = rb + wr * 16 + l4 * 4 + q;
                int cg = j * 64 + wc * 32 + f * 16 + l15;
                pO[((size_t)gm * SPLITS + split) * C_DIM + cg] = of[j][f][q];
            }
    if (wc == 0 && l15 == 0) {
#pragma unroll
        for (int q = 0; q < 4; ++q) {
            int gm = rb + wr * 16 + l4 * 4 + q;
            pM[gm * SPLITS + split] = Mr[q];
            pL[gm * SPLITS + split] = Lr[q];
        }
    }
}

// ======================= split-K combine =======================
__global__ void k_combine(const float* __restrict__ pO, const float* __restrict__ pM,
                          const float* __restrict__ pL, const float4* __restrict__ rowp,
                          float* __restrict__ out) {
    int r = blockIdx.x;
    int tid = threadIdx.x;   // 128 threads, 4 c's each
    float ce = rowp[r].z;
    float Ms[SPLITS], Ls[SPLITS];
    float M = -1e30f;
#pragma unroll
    for (int s = 0; s < SPLITS; ++s) {
        Ms[s] = pM[r * SPLITS + s];
        Ls[s] = pL[r * SPLITS + s];
        M = fmaxf(M, Ms[s]);
    }
    float es[SPLITS], L = 0.f;
#pragma unroll
    for (int s = 0; s < SPLITS; ++s) { es[s] = exp2f((Ms[s] - M) * ce); L += Ls[s] * es[s]; }
    float invL = 1.0f / L;
    f32x4 acc = (f32x4){0.f, 0.f, 0.f, 0.f};
#pragma unroll
    for (int s = 0; s < SPLITS; ++s) {
        f32x4 v = *(const f32x4*)(pO + ((size_t)r * SPLITS + s) * C_DIM + tid * 4);
        acc += v * es[s];
    }
    acc *= invL;
    *(f32x4*)(out + (size_t)r * C_DIM + tid * 4) = acc;
}

// ======================= launch =======================
extern "C" void kernel_launch(void* const* d_in, const int* in_sizes, int n_in,
                              void* d_out, int out_size, void* d_ws, size_t ws_size,
                              hipStream_t stream) {
    const float* x = (const float*)d_in[0];
    const int* t = (const int*)d_in[1];
    const float* A = (const float*)d_in[2];
    const float* bar_alpha = (const float*)d_in[3];
    float* out = (float*)d_out;
    char* ws = (char*)d_ws;
    if (ws_size < WS_NEED) return;

    char* imgA = ws + OFF_IMGA;
    char* imgC = ws + OFF_IMGC;
    unsigned short* Xh = (unsigned short*)(ws + OFF_XH);
    unsigned short* Xl = (unsigned short*)(ws + OFF_XL);
    float* Asq = (float*)(ws + OFF_ASQ);
    float4* rowp = (float4*)(ws + OFF_ROWP);
    float* pO = (float*)(ws + OFF_PO);
    float* pM = (float*)(ws + OFF_PM);
    float* pL = (float*)(ws + OFF_PL);

    (void)hipFuncSetAttribute((const void*)k_fused,
                              hipFuncAttributeMaxDynamicSharedMemorySize, SM_TOT);

    k_rows<<<R_DIM / 256, 256, 0, stream>>>(t, bar_alpha, rowp);
    k_splitx<<<(R_DIM * C_DIM / 8) / 256, 256, 0, stream>>>(x, (us8*)Xh, (us8*)Xl);
    k_imgA<<<GTILES * 8, 256, 0, stream>>>(A, imgA);
    k_imgC<<<GTILES * 8, 256, 0, stream>>>(A, imgC);
    k_asq<<<K_DIM / 4, 256, 0, stream>>>(A, Asq);
    k_fused<<<(R_DIM / BM) * SPLITS, 512, SM_TOT, stream>>>(imgA, imgC, Xh, Xl,
                                                            Asq, rowp, pO, pM, pL);
    k_combine<<<R_DIM, 128, 0, stream>>>(pO, pM, pL, rowp, out);
}